// Round 3
// baseline (77.217 us; speedup 1.0000x reference)
//
#include <hip/hip_runtime.h>
#include <hip/hip_cooperative_groups.h>

namespace cg = cooperative_groups;

// Problem constants (b=256, c_cls=1, h=w=192)
#define B_       256
#define W_       192
#define HW_      36864          // 192*192
#define SCALE_   191.0f         // h-1 == w-1
#define CHUNKS_  4              // chunks per sample
#define NBLK_    (B_ * CHUNKS_) // 1024 blocks: 4 per CU, always co-resident
#define NTHR_    256
#define CHUNK_V4_ 2304          // (HW_/4)/CHUNKS_
#define V4_PER_THREAD_ 9        // 2304/256

__global__ __launch_bounds__(NTHR_, 4)
void locloss_coop(const float* __restrict__ cls,
                  const float* __restrict__ loc,
                  const float* __restrict__ cr,
                  float* __restrict__ out,
                  float2* __restrict__ ws) {
    const int blk = blockIdx.x;
    const int b   = blk >> 2;        // sample
    const int s   = blk & 3;         // chunk within sample
    const int t   = threadIdx.x;

    // ---- Phase 1: partial argmax over this (sample, chunk) ----
    const float4* __restrict__ c4 =
        (const float4*)cls + (size_t)b * (HW_ / 4) + (size_t)s * CHUNK_V4_;
    const int elem_base = s * (CHUNK_V4_ * 4);

    float bv = -INFINITY;
    int   bi = 0x7FFFFFFF;

#pragma unroll
    for (int it = 0; it < V4_PER_THREAD_; ++it) {
        const int v = t + it * NTHR_;
        const float4 x = c4[v];
        const int base = elem_base + v * 4;
        if (x.x > bv || (x.x == bv && base     < bi)) { bv = x.x; bi = base;     }
        if (x.y > bv || (x.y == bv && base + 1 < bi)) { bv = x.y; bi = base + 1; }
        if (x.z > bv || (x.z == bv && base + 2 < bi)) { bv = x.z; bi = base + 2; }
        if (x.w > bv || (x.w == bv && base + 3 < bi)) { bv = x.w; bi = base + 3; }
    }

    // wave (64-lane) reduction: max value, smallest index on ties
#pragma unroll
    for (int off = 32; off >= 1; off >>= 1) {
        const float ov = __shfl_down(bv, off);
        const int   oi = __shfl_down(bi, off);
        if (ov > bv || (ov == bv && oi < bi)) { bv = ov; bi = oi; }
    }

    __shared__ float sv[NTHR_ / 64];
    __shared__ int   si[NTHR_ / 64];
    const int wid = t >> 6;
    if ((t & 63) == 0) { sv[wid] = bv; si[wid] = bi; }
    __syncthreads();

    if (t == 0) {
#pragma unroll
        for (int wv = 1; wv < NTHR_ / 64; ++wv) {
            if (sv[wv] > bv || (sv[wv] == bv && si[wv] < bi)) { bv = sv[wv]; bi = si[wv]; }
        }
        ws[blk] = make_float2(bv, __int_as_float(bi));
        __threadfence();   // make partial visible device-wide before grid sync
    }

    cg::this_grid().sync();

    // ---- Phase 2: block 0 combines partials, gathers, reduces to mean ----
    if (blk == 0) {
        // thread t handles sample t
        float mv = -INFINITY;
        int   mi = 0x7FFFFFFF;
#pragma unroll
        for (int sc = 0; sc < CHUNKS_; ++sc) {   // ascending chunk order:
            const float2 p = ws[t * CHUNKS_ + sc];
            const float v = p.x;                 // strict > keeps first occurrence
            if (v > mv) { mv = v; mi = __float_as_int(p.y); }
        }

        const int r = mi / W_;
        const int c = mi - r * W_;

        const size_t lbase = (size_t)t * 2 * HW_ + (size_t)r * W_ + c;
        const float l0 = loc[lbase];
        const float l1 = loc[lbase + HW_];

        const float bias0 = cr[2 * t]     * SCALE_ - (float)r;
        const float bias1 = cr[2 * t + 1] * SCALE_ - (float)c;

        const float d0 = fabsf(l0 - bias0);
        const float d1 = fabsf(l1 - bias1);
        const float s0 = (d0 < 1.0f) ? 0.5f * d0 * d0 : d0 - 0.5f;
        const float s1 = (d1 < 1.0f) ? 0.5f * d1 * d1 : d1 - 0.5f;
        float v = s0 + s1;

#pragma unroll
        for (int off = 32; off >= 1; off >>= 1) v += __shfl_down(v, off);

        __shared__ float sh[4];
        if ((t & 63) == 0) sh[t >> 6] = v;
        __syncthreads();
        if (t == 0) out[0] = (sh[0] + sh[1] + sh[2] + sh[3]) * (1.0f / (2.0f * B_));
    }
}

extern "C" void kernel_launch(void* const* d_in, const int* in_sizes, int n_in,
                              void* d_out, int out_size, void* d_ws, size_t ws_size,
                              hipStream_t stream) {
    const float* cls = (const float*)d_in[0];   // (256,1,192,192) f32
    const float* loc = (const float*)d_in[1];   // (256,2,192,192) f32
    const float* cr  = (const float*)d_in[2];   // (256,2) f32
    float* out = (float*)d_out;
    float2* ws = (float2*)d_ws;                 // 1024 float2 = 8 KB used

    void* args[] = {(void*)&cls, (void*)&loc, (void*)&cr, (void*)&out, (void*)&ws};
    hipLaunchCooperativeKernel((const void*)locloss_coop,
                               dim3(NBLK_), dim3(NTHR_), args, 0, stream);
}